// Round 1
// baseline (457.249 us; speedup 1.0000x reference)
//
#include <hip/hip_runtime.h>
#include <hip/hip_bf16.h>

// RNN-T joiner: out[b,t,u,v] = sum_k relu(x[b,t,k]+y[b,u,k]) * W[v,k] + bias[v]
// GEMM view: M=B*T*U=131072, N=V=1024, K=D=512, A generated on the fly.
// bf16 MFMA (16x16x32), fp32 accumulate. 128x128 tile, BK=64, 4 waves (2x2).
// LDS XOR-swizzle (slot ^ row&7) to avoid 16-way bank conflicts on ds_read_b128.

constexpr int Bc = 8, Tc = 256, Uc = 64, Dc = 512, Vc = 1024;
constexpr int BM = 128, BN = 128, BK = 64;
constexpr int MT = (Bc * Tc * Uc) / BM;  // 1024 M-tiles
constexpr int NT = Vc / BN;              // 8 N-tiles
constexpr int BDIM = 256;                // 4 waves

typedef __attribute__((ext_vector_type(8))) short short8;     // 8 bf16 (4 VGPRs)
typedef __attribute__((ext_vector_type(8))) unsigned short ushort8;
typedef __attribute__((ext_vector_type(4))) float f32x4;

__device__ inline unsigned short f2bf(float f) {
    union { float f; unsigned u; } v; v.f = f;
    unsigned r = v.u + 0x7FFFu + ((v.u >> 16) & 1u);  // RNE
    return (unsigned short)(r >> 16);
}

__global__ __launch_bounds__(BDIM) void joiner_mfma(
    const float* __restrict__ x, const float* __restrict__ y,
    const float* __restrict__ W, const float* __restrict__ bias,
    float* __restrict__ out)
{
    __shared__ unsigned short As[BM * BK];  // 16 KB, swizzled
    __shared__ unsigned short Ws[BN * BK];  // 16 KB, swizzled

    const int tid = threadIdx.x;
    const int mtile = blockIdx.x % MT;
    const int ntile = blockIdx.x / MT;
    const int m0 = mtile * BM;
    const int v0 = ntile * BN;
    const int bb = m0 / (Tc * Uc);        // tile never crosses batch (16384 % 128 == 0)
    const int t0 = (m0 % (Tc * Uc)) / Uc; // rows cover t0, t0+1 (u = row & 63)

    const int lane = tid & 63;
    const int wid  = tid >> 6;
    const int wm = wid >> 1, wn = wid & 1;   // 2x2 wave grid, 64x64 each
    const int lr  = lane & 15;               // frag row/col
    const int lk8 = lane >> 4;               // k-octet within 32 (0..3)

    f32x4 acc[4][4] = {};  // 4x4 frags of 16x16 -> 64 fp32/lane

    for (int k0 = 0; k0 < Dc; k0 += BK) {
        __syncthreads();  // previous-iter LDS reads done before overwrite
        // ---- stage A (relu(x+y) -> bf16) and W (fp32 -> bf16), XOR-swizzled ----
        #pragma unroll
        for (int i = 0; i < 4; ++i) {
            const int chunk = tid + i * BDIM;   // 0..1023: 128 rows x 8 slots
            const int row  = chunk >> 3;
            const int slot = chunk & 7;
            const int ps8  = (slot ^ (row & 7)) * 8;  // swizzled element offset

            // A: row -> (t, u)
            const int t = t0 + (row >> 6);
            const int u = row & 63;
            const float4* xp = (const float4*)(x + ((size_t)(bb * Tc + t) * Dc + k0 + slot * 8));
            const float4* yp = (const float4*)(y + ((size_t)(bb * Uc + u) * Dc + k0 + slot * 8));
            float4 xa = xp[0], xb2 = xp[1];
            float4 ya = yp[0], yb2 = yp[1];
            ushort8 hv;
            hv[0] = f2bf(fmaxf(xa.x + ya.x, 0.f));
            hv[1] = f2bf(fmaxf(xa.y + ya.y, 0.f));
            hv[2] = f2bf(fmaxf(xa.z + ya.z, 0.f));
            hv[3] = f2bf(fmaxf(xa.w + ya.w, 0.f));
            hv[4] = f2bf(fmaxf(xb2.x + yb2.x, 0.f));
            hv[5] = f2bf(fmaxf(xb2.y + yb2.y, 0.f));
            hv[6] = f2bf(fmaxf(xb2.z + yb2.z, 0.f));
            hv[7] = f2bf(fmaxf(xb2.w + yb2.w, 0.f));
            *(ushort8*)(&As[row * BK + ps8]) = hv;

            // W: row -> v
            const float4* wp = (const float4*)(W + ((size_t)(v0 + row) * Dc + k0 + slot * 8));
            float4 wa = wp[0], wb2 = wp[1];
            ushort8 wv;
            wv[0] = f2bf(wa.x); wv[1] = f2bf(wa.y); wv[2] = f2bf(wa.z); wv[3] = f2bf(wa.w);
            wv[4] = f2bf(wb2.x); wv[5] = f2bf(wb2.y); wv[6] = f2bf(wb2.z); wv[7] = f2bf(wb2.w);
            *(ushort8*)(&Ws[row * BK + ps8]) = wv;
        }
        __syncthreads();

        // ---- MFMA inner loop: 2 K-steps of 32, 16 MFMAs each ----
        #pragma unroll
        for (int kk = 0; kk < 2; ++kk) {
            const int psk = kk * 4 + lk8;  // k-octet slot index (0..7)
            short8 af[4], bfr[4];
            #pragma unroll
            for (int mf = 0; mf < 4; ++mf) {
                const int row = wm * 64 + mf * 16 + lr;
                af[mf] = *(const short8*)(&As[row * BK + ((psk ^ (row & 7)) * 8)]);
            }
            #pragma unroll
            for (int nf = 0; nf < 4; ++nf) {
                const int row = wn * 64 + nf * 16 + lr;
                bfr[nf] = *(const short8*)(&Ws[row * BK + ((psk ^ (row & 7)) * 8)]);
            }
            #pragma unroll
            for (int mf = 0; mf < 4; ++mf)
                #pragma unroll
                for (int nf = 0; nf < 4; ++nf)
                    acc[mf][nf] = __builtin_amdgcn_mfma_f32_16x16x32_bf16(
                        af[mf], bfr[nf], acc[mf][nf], 0, 0, 0);
        }
    }

    // ---- epilogue: C/D layout col=lane&15, row=(lane>>4)*4+reg ----
    #pragma unroll
    for (int nf = 0; nf < 4; ++nf) {
        const int v = v0 + wn * 64 + nf * 16 + lr;
        const float bv = bias[v];
        #pragma unroll
        for (int mf = 0; mf < 4; ++mf) {
            const int mrow = m0 + wm * 64 + mf * 16 + (lane >> 4) * 4;
            #pragma unroll
            for (int j = 0; j < 4; ++j) {
                out[(size_t)(mrow + j) * Vc + v] = acc[mf][nf][j] + bv;
            }
        }
    }
}

extern "C" void kernel_launch(void* const* d_in, const int* in_sizes, int n_in,
                              void* d_out, int out_size, void* d_ws, size_t ws_size,
                              hipStream_t stream) {
    const float* x = (const float*)d_in[0];
    const float* y = (const float*)d_in[1];
    const float* W = (const float*)d_in[2];
    const float* b = (const float*)d_in[3];
    float* out = (float*)d_out;

    dim3 grid(MT * NT);  // 8192 blocks
    joiner_mfma<<<grid, BDIM, 0, stream>>>(x, y, W, b, out);
}